// Round 1
// baseline (471.933 us; speedup 1.0000x reference)
//
#include <hip/hip_runtime.h>
#include <math.h>

#define NQ     9
#define NSTATE 512
#define B_DIM  48
#define S_DIM  96
#define D_DIM  54
#define DENC   4
#define DVAR   8
#define NFLAT  (B_DIM * S_DIM)   // 4608

__device__ __forceinline__ float wave_sum(float v) {
#pragma unroll
    for (int m = 32; m >= 1; m >>= 1) v += __shfl_xor(v, m, 64);
    return v;
}

// Apply a rotation gate on qubit with bit position `bit` (bit = 8 - qubit).
// RX: [[c,-is],[-is,c]]  RY: [[c,-s],[s,c]]
template <bool RX>
__device__ __forceinline__ void rot_gate(float2* st, int bit, float c, float s, int t) {
    const int m = 1 << bit;
#pragma unroll
    for (int k = 0; k < 4; ++k) {
        int p  = t + 64 * k;                       // pair index 0..255
        int i0 = ((p >> bit) << (bit + 1)) | (p & (m - 1));
        int i1 = i0 | m;
        float2 a  = st[i0];
        float2 bb = st[i1];
        float2 n0, n1;
        if (RX) {
            n0.x = c * a.x + s * bb.y;  n0.y = c * a.y - s * bb.x;
            n1.x = c * bb.x + s * a.y;  n1.y = c * bb.y - s * a.x;
        } else {
            n0.x = c * a.x - s * bb.x;  n0.y = c * a.y - s * bb.y;
            n1.x = s * a.x + c * bb.x;  n1.y = s * a.y + c * bb.y;
        }
        st[i0] = n0;
        st[i1] = n1;
    }
    __syncthreads();
}

// CNOT: control mask cmask (single bit), target bit position tbit.
__device__ __forceinline__ void cnot_gate(float2* st, int cmask, int tbit, int t) {
    const int m = 1 << tbit;
#pragma unroll
    for (int k = 0; k < 4; ++k) {
        int p  = t + 64 * k;
        int i0 = ((p >> tbit) << (tbit + 1)) | (p & (m - 1));
        if (i0 & cmask) {
            int i1 = i0 | m;
            float2 a = st[i0];
            st[i0] = st[i1];
            st[i1] = a;
        }
    }
    __syncthreads();
}

// cs points at LDS table of {cos(t/2), sin(t/2)}: [0..17] initial RX/RY pairs,
// [18..18+9*layers) per-layer RY angles.
__device__ void run_circuit(float2* st, const float2* cs, int layers, int t) {
    for (int j = 0; j < NQ; ++j) {
        float2 c0 = cs[2 * j];
        float2 c1 = cs[2 * j + 1];
        rot_gate<true >(st, 8 - j, c0.x, c0.y, t);
        rot_gate<false>(st, 8 - j, c1.x, c1.y, t);
    }
    int idx = 18;
    for (int L = 0; L < layers; ++L) {
        for (int j = 0; j < NQ; ++j) {
            int cbit = 8 - j;
            int tbit = 8 - ((j + 1) % NQ);
            cnot_gate(st, 1 << cbit, tbit, t);
        }
        for (int j = 0; j < NQ; ++j) {
            float2 cc = cs[idx++];
            rot_gate<false>(st, 8 - j, cc.x, cc.y, t);
        }
    }
}

__global__ __launch_bounds__(64) void sim_kernel(
    const float* __restrict__ inp, const float* __restrict__ wq,
    const float* __restrict__ wk,  const float* __restrict__ wv,
    float* __restrict__ outQ, float* __restrict__ outK, float* __restrict__ outV)
{
    __shared__ float2 st[NSTATE];
    __shared__ float2 enc[NSTATE];
    __shared__ float2 cs[54 + 3 * 90];   // {cos(t/2), sin(t/2)}

    const int fi = blockIdx.x;           // flat = s*B + b
    const int t  = threadIdx.x;
    const int b  = fi % B_DIM;
    const int s  = fi / B_DIM;
    const float* x = inp + ((size_t)b * S_DIM + s) * D_DIM;

    // Precompute angle tables: 54 input angles + 3x90 weight angles.
    for (int k = t; k < 54 + 270; k += 64) {
        float ang;
        if (k < 54) {
            ang = x[k];
        } else {
            int w = k - 54;
            const float* p = (w < 90) ? wq : (w < 180 ? wk : wv);
            ang = p[w % 90];
        }
        float sn, cn;
        sincosf(0.5f * ang, &sn, &cn);
        cs[k] = make_float2(cn, sn);
    }
    // Init |0...0>
    for (int i = t; i < NSTATE; i += 64)
        st[i] = (i == 0) ? make_float2(1.f, 0.f) : make_float2(0.f, 0.f);
    __syncthreads();

    // Shared encoding circuit, then checkpoint.
    run_circuit(st, cs, DENC, t);
    for (int i = t; i < NSTATE; i += 64) enc[i] = st[i];
    __syncthreads();

    for (int c = 0; c < 3; ++c) {
        if (c > 0) {
            for (int i = t; i < NSTATE; i += 64) st[i] = enc[i];
            __syncthreads();
        }
        run_circuit(st, cs + 54 + c * 90, DVAR, t);

        if (c < 2) {
            // <Z_0> : qubit 0 is bit 8 (mask 256)
            float z = 0.f;
            for (int i = t; i < NSTATE; i += 64) {
                float2 a = st[i];
                float p = a.x * a.x + a.y * a.y;
                z += (i & 256) ? -p : p;
            }
            z = wave_sum(z);
            if (t == 0) {
                if (c == 0) outQ[fi] = z; else outK[fi] = z;
            }
            __syncthreads();
        } else {
            // V: <Z_q>, <X_q>, <Y_q> for q=0..8; output pattern Z9,X9,Y9 repeated twice.
            for (int q = 0; q < NQ; ++q) {
                const int bit = 8 - q, m = 1 << bit;
                float ez = 0.f, ex = 0.f, ey = 0.f;
#pragma unroll
                for (int k = 0; k < 4; ++k) {
                    int p  = t + 64 * k;
                    int i0 = ((p >> bit) << (bit + 1)) | (p & (m - 1));
                    int i1 = i0 | m;
                    float2 a  = st[i0];
                    float2 bb = st[i1];
                    ez += (a.x * a.x + a.y * a.y) - (bb.x * bb.x + bb.y * bb.y);
                    ex += 2.f * (a.x * bb.x + a.y * bb.y);
                    ey += 2.f * (a.x * bb.y - a.y * bb.x);
                }
                ez = wave_sum(ez); ex = wave_sum(ex); ey = wave_sum(ey);
                if (t == 0) {
                    float* vrow = outV + (size_t)fi * D_DIM;
                    vrow[q]      = ez; vrow[9 + q]  = ex; vrow[18 + q] = ey;
                    vrow[27 + q] = ez; vrow[36 + q] = ex; vrow[45 + q] = ey;
                }
            }
        }
    }
}

__global__ __launch_bounds__(64) void attn_kernel(
    const float* __restrict__ inp, const float* __restrict__ Q,
    const float* __restrict__ K,   const float* __restrict__ V,
    float* __restrict__ out)
{
    __shared__ float w[S_DIM];
    const int bi = blockIdx.x;         // b*S + i
    const int b  = bi / S_DIM;
    const int i  = bi % S_DIM;
    const int t  = threadIdx.x;

    const float q = Q[i * B_DIM + b];
    for (int j = t; j < S_DIM; j += 64) {
        float diff = q - K[j * B_DIM + b];
        w[j] = expf(-diff * diff);
    }
    __syncthreads();

    float ps = 0.f;
    for (int j = t; j < S_DIM; j += 64) ps += w[j];
    ps = wave_sum(ps);
    const float inv = 1.f / ps;

    if (t < D_DIM) {
        float acc = 0.f;
        for (int j = 0; j < S_DIM; ++j)
            acc += w[j] * V[(size_t)(j * B_DIM + b) * D_DIM + t];
        size_t o = (size_t)bi * D_DIM + t;
        out[o] = inp[o] + acc * inv;
    }
}

extern "C" void kernel_launch(void* const* d_in, const int* in_sizes, int n_in,
                              void* d_out, int out_size, void* d_ws, size_t ws_size,
                              hipStream_t stream)
{
    (void)in_sizes; (void)n_in; (void)out_size; (void)ws_size;
    const float* inp = (const float*)d_in[0];
    const float* wq  = (const float*)d_in[1];
    const float* wk  = (const float*)d_in[2];
    const float* wv  = (const float*)d_in[3];
    float* outp = (float*)d_out;

    float* Qw = (float*)d_ws;
    float* Kw = Qw + NFLAT;
    float* Vw = Kw + NFLAT;

    sim_kernel<<<NFLAT, 64, 0, stream>>>(inp, wq, wk, wv, Qw, Kw, Vw);
    attn_kernel<<<NFLAT, 64, 0, stream>>>(inp, Qw, Kw, Vw, outp);
}

// Round 2
// 321.839 us; speedup vs baseline: 1.4664x; 1.4664x over previous
//
#include <hip/hip_runtime.h>
#include <math.h>

#define NQ     9
#define B_DIM  48
#define S_DIM  96
#define D_DIM  54
#define DENC   4
#define DVAR   8
#define NFLAT  (B_DIM * S_DIM)   // 4608

__device__ __forceinline__ float wave_sum(float v) {
#pragma unroll
    for (int m = 32; m >= 1; m >>= 1) v += __shfl_xor(v, m, 64);
    return v;
}

// State layout: amplitude index i (9 bits) -> lane = i>>3 (bits 8..3), reg r = i&7 (bits 2..0).
// Qubit j <-> state bit BJ = 8-j.
// RX: n0 = c*a + s*(b.y,-b.x)[i.e. -i*s*b]; n1 symmetric.  RY: n0 = c*a - s*b; n1 = s*a + c*b.

template<int BJ, bool RX>
__device__ __forceinline__ void rot(float2 st[8], float c, float s, int lane) {
    if constexpr (BJ >= 3) {
        constexpr int lm = 1 << (BJ - 3);
        const float sgn = (lane & lm) ? s : -s;   // RY only
#pragma unroll
        for (int r = 0; r < 8; ++r) {
            float px = __shfl_xor(st[r].x, lm, 64);
            float py = __shfl_xor(st[r].y, lm, 64);
            float nx, ny;
            if constexpr (RX) { nx = c * st[r].x + s * py;   ny = c * st[r].y - s * px; }
            else              { nx = c * st[r].x + sgn * px; ny = c * st[r].y + sgn * py; }
            st[r].x = nx; st[r].y = ny;
        }
    } else {
        constexpr int M = 1 << BJ;
#pragma unroll
        for (int r = 0; r < 8; ++r) {
            if ((r & M) == 0) {
                float2 a = st[r], b = st[r + M];
                if constexpr (RX) {
                    st[r].x     = c * a.x + s * b.y;  st[r].y     = c * a.y - s * b.x;
                    st[r + M].x = c * b.x + s * a.y;  st[r + M].y = c * b.y - s * a.x;
                } else {
                    st[r].x     = c * a.x - s * b.x;  st[r].y     = c * a.y - s * b.y;
                    st[r + M].x = s * a.x + c * b.x;  st[r + M].y = s * a.y + c * b.y;
                }
            }
        }
    }
}

// CNOT with control state-bit CB, target state-bit TB.
template<int CB, int TB>
__device__ __forceinline__ void cnot(float2 st[8], int lane) {
    if constexpr (CB >= 3 && TB >= 3) {
        constexpr int tlm = 1 << (TB - 3);
        const bool ctrl = (lane >> (CB - 3)) & 1;
#pragma unroll
        for (int r = 0; r < 8; ++r) {
            float px = __shfl_xor(st[r].x, tlm, 64);
            float py = __shfl_xor(st[r].y, tlm, 64);
            if (ctrl) { st[r].x = px; st[r].y = py; }
        }
    } else if constexpr (CB >= 3 && TB < 3) {
        constexpr int M = 1 << TB;
        const bool ctrl = (lane >> (CB - 3)) & 1;
#pragma unroll
        for (int r = 0; r < 8; ++r) {
            if ((r & M) == 0) {
                float2 a = st[r], b = st[r + M];
                st[r].x     = ctrl ? b.x : a.x;  st[r].y     = ctrl ? b.y : a.y;
                st[r + M].x = ctrl ? a.x : b.x;  st[r + M].y = ctrl ? a.y : b.y;
            }
        }
    } else if constexpr (CB < 3 && TB < 3) {
        constexpr int CM = 1 << CB, M = 1 << TB;
#pragma unroll
        for (int r = 0; r < 8; ++r) {
            if ((r & CM) && !(r & M)) { float2 t = st[r]; st[r] = st[r + M]; st[r + M] = t; }
        }
    } else {  // CB < 3, TB >= 3: control is a reg bit -> unconditional cross-lane swap for those regs
        constexpr int CM = 1 << CB;
        constexpr int tlm = 1 << (TB - 3);
#pragma unroll
        for (int r = 0; r < 8; ++r) {
            if (r & CM) {
                st[r].x = __shfl_xor(st[r].x, tlm, 64);
                st[r].y = __shfl_xor(st[r].y, tlm, 64);
            }
        }
    }
}

// CNOT ring: control qubit j, target qubit (j+1)%9, j = 0..8  -> bits (8,7)(7,6)...(1,0)(0,8)
__device__ __forceinline__ void ring(float2 st[8], int lane) {
    cnot<8, 7>(st, lane); cnot<7, 6>(st, lane); cnot<6, 5>(st, lane);
    cnot<5, 4>(st, lane); cnot<4, 3>(st, lane); cnot<3, 2>(st, lane);
    cnot<2, 1>(st, lane); cnot<1, 0>(st, lane); cnot<0, 8>(st, lane);
}

#define INITQ(j) { float2 c0 = cs[2 * (j)], c1 = cs[2 * (j) + 1];      \
                   rot<8 - (j), true >(st, c0.x, c0.y, lane);          \
                   rot<8 - (j), false>(st, c1.x, c1.y, lane); }

__device__ __forceinline__ void run_circuit(float2 st[8], const float2* cs, int layers, int lane) {
    INITQ(0) INITQ(1) INITQ(2) INITQ(3) INITQ(4)
    INITQ(5) INITQ(6) INITQ(7) INITQ(8)
    const float2* p = cs + 18;
#pragma unroll 1
    for (int L = 0; L < layers; ++L) {
        ring(st, lane);
        { float2 cc = p[0]; rot<8, false>(st, cc.x, cc.y, lane); }
        { float2 cc = p[1]; rot<7, false>(st, cc.x, cc.y, lane); }
        { float2 cc = p[2]; rot<6, false>(st, cc.x, cc.y, lane); }
        { float2 cc = p[3]; rot<5, false>(st, cc.x, cc.y, lane); }
        { float2 cc = p[4]; rot<4, false>(st, cc.x, cc.y, lane); }
        { float2 cc = p[5]; rot<3, false>(st, cc.x, cc.y, lane); }
        { float2 cc = p[6]; rot<2, false>(st, cc.x, cc.y, lane); }
        { float2 cc = p[7]; rot<1, false>(st, cc.x, cc.y, lane); }
        { float2 cc = p[8]; rot<0, false>(st, cc.x, cc.y, lane); }
        p += 9;
    }
}

// <Z>, <X>, <Y> on qubit with state-bit BJ.
template<int BJ>
__device__ __forceinline__ void expv(const float2 st[8], int lane, float& ez, float& ex, float& ey) {
    ez = ex = ey = 0.f;
    if constexpr (BJ >= 3) {
        constexpr int lm = 1 << (BJ - 3);
        const float sgn = (lane & lm) ? -1.f : 1.f;
#pragma unroll
        for (int r = 0; r < 8; ++r) {
            float px = __shfl_xor(st[r].x, lm, 64);
            float py = __shfl_xor(st[r].y, lm, 64);
            ez += sgn * (st[r].x * st[r].x + st[r].y * st[r].y);
            ex += st[r].x * px + st[r].y * py;            // both halves contribute Re once -> 2Re total
            ey += sgn * (st[r].x * py - st[r].y * px);    // both halves contribute Im once -> 2Im total
        }
    } else {
        constexpr int M = 1 << BJ;
#pragma unroll
        for (int r = 0; r < 8; ++r) {
            if ((r & M) == 0) {
                float2 a = st[r], b = st[r + M];
                ez += (a.x * a.x + a.y * a.y) - (b.x * b.x + b.y * b.y);
                ex += 2.f * (a.x * b.x + a.y * b.y);
                ey += 2.f * (a.x * b.y - a.y * b.x);
            }
        }
    }
    ez = wave_sum(ez); ex = wave_sum(ex); ey = wave_sum(ey);
}

__global__ __launch_bounds__(64) void sim_kernel(
    const float* __restrict__ inp, const float* __restrict__ wq,
    const float* __restrict__ wk,  const float* __restrict__ wv,
    float* __restrict__ outQ, float* __restrict__ outK, float* __restrict__ outV)
{
    __shared__ float2 cs[54 + 270];   // {cos(t/2), sin(t/2)} per angle

    const int fi   = blockIdx.x;      // flat = s*B + b
    const int lane = threadIdx.x;
    const int b = fi % B_DIM, s = fi / B_DIM;
    const float* x = inp + ((size_t)b * S_DIM + s) * D_DIM;

    for (int k = lane; k < 324; k += 64) {
        float ang = (k < 54)  ? x[k]
                  : (k < 144) ? wq[k - 54]
                  : (k < 234) ? wk[k - 144]
                              : wv[k - 234];
        float sn, cn; sincosf(0.5f * ang, &sn, &cn);
        cs[k] = make_float2(cn, sn);
    }
    __syncthreads();

    float2 st[8], ck[8];
#pragma unroll
    for (int r = 0; r < 8; ++r) st[r] = make_float2(0.f, 0.f);
    if (lane == 0) st[0].x = 1.f;

    // Shared encoding circuit, checkpoint in registers.
    run_circuit(st, cs, DENC, lane);
#pragma unroll
    for (int r = 0; r < 8; ++r) ck[r] = st[r];

    // ---- Q ----
    run_circuit(st, cs + 54, DVAR, lane);
    {
        float p = 0.f;
#pragma unroll
        for (int r = 0; r < 8; ++r) p += st[r].x * st[r].x + st[r].y * st[r].y;
        p = (lane & 32) ? -p : p;     // qubit 0 = state bit 8 = lane bit 5
        p = wave_sum(p);
        if (lane == 0) outQ[fi] = p;
    }

    // ---- K ----
#pragma unroll
    for (int r = 0; r < 8; ++r) st[r] = ck[r];
    run_circuit(st, cs + 144, DVAR, lane);
    {
        float p = 0.f;
#pragma unroll
        for (int r = 0; r < 8; ++r) p += st[r].x * st[r].x + st[r].y * st[r].y;
        p = (lane & 32) ? -p : p;
        p = wave_sum(p);
        if (lane == 0) outK[fi] = p;
    }

    // ---- V ----
#pragma unroll
    for (int r = 0; r < 8; ++r) st[r] = ck[r];
    run_circuit(st, cs + 234, DVAR, lane);
    {
        float* vrow = outV + (size_t)fi * D_DIM;
#define EXPQ(q) { float ez, ex, ey; expv<8 - (q)>(st, lane, ez, ex, ey);            \
                  if (lane == 0) { vrow[(q)] = ez; vrow[9 + (q)] = ex;              \
                                   vrow[18 + (q)] = ey; vrow[27 + (q)] = ez;        \
                                   vrow[36 + (q)] = ex; vrow[45 + (q)] = ey; } }
        EXPQ(0) EXPQ(1) EXPQ(2) EXPQ(3) EXPQ(4)
        EXPQ(5) EXPQ(6) EXPQ(7) EXPQ(8)
#undef EXPQ
    }
}

__global__ __launch_bounds__(64) void attn_kernel(
    const float* __restrict__ inp, const float* __restrict__ Q,
    const float* __restrict__ K,   const float* __restrict__ V,
    float* __restrict__ out)
{
    __shared__ float w[S_DIM];
    const int bi = blockIdx.x;         // b*S + i
    const int b  = bi / S_DIM;
    const int i  = bi % S_DIM;
    const int t  = threadIdx.x;

    const float q = Q[i * B_DIM + b];
    for (int j = t; j < S_DIM; j += 64) {
        float diff = q - K[j * B_DIM + b];
        w[j] = expf(-diff * diff);
    }
    __syncthreads();

    float ps = 0.f;
    for (int j = t; j < S_DIM; j += 64) ps += w[j];
    ps = wave_sum(ps);
    const float inv = 1.f / ps;

    if (t < D_DIM) {
        float acc = 0.f;
        for (int j = 0; j < S_DIM; ++j)
            acc += w[j] * V[(size_t)(j * B_DIM + b) * D_DIM + t];
        size_t o = (size_t)bi * D_DIM + t;
        out[o] = inp[o] + acc * inv;
    }
}

extern "C" void kernel_launch(void* const* d_in, const int* in_sizes, int n_in,
                              void* d_out, int out_size, void* d_ws, size_t ws_size,
                              hipStream_t stream)
{
    (void)in_sizes; (void)n_in; (void)out_size; (void)ws_size;
    const float* inp = (const float*)d_in[0];
    const float* wq  = (const float*)d_in[1];
    const float* wk  = (const float*)d_in[2];
    const float* wv  = (const float*)d_in[3];
    float* outp = (float*)d_out;

    float* Qw = (float*)d_ws;
    float* Kw = Qw + NFLAT;
    float* Vw = Kw + NFLAT;

    sim_kernel<<<NFLAT, 64, 0, stream>>>(inp, wq, wk, wv, Qw, Kw, Vw);
    attn_kernel<<<NFLAT, 64, 0, stream>>>(inp, Qw, Kw, Vw, outp);
}

// Round 4
// 208.170 us; speedup vs baseline: 2.2671x; 1.5460x over previous
//
#include <hip/hip_runtime.h>
#include <math.h>

#define NQ     9
#define B_DIM  48
#define S_DIM  96
#define D_DIM  54
#define DENC   4
#define DVAR   8
#define NFLAT  (B_DIM * S_DIM)   // 4608

// ---- VALU lane-xor permutes (avoid the shared per-CU LDS pipe) ----
// xor1/xor2: DPP quad_perm; xor8: DPP ROW_ROR:8; xor16/32: gfx950 permlane*_swap;
// xor4: ds_swizzle (no VALU form).
template<int LM>
__device__ __forceinline__ float lxor(float v, int lane) {
    int x = __float_as_int(v);
    if constexpr (LM == 1) {
        x = __builtin_amdgcn_update_dpp(x, x, 0xB1, 0xF, 0xF, true);   // quad_perm [1,0,3,2]
    } else if constexpr (LM == 2) {
        x = __builtin_amdgcn_update_dpp(x, x, 0x4E, 0xF, 0xF, true);   // quad_perm [2,3,0,1]
    } else if constexpr (LM == 4) {
        x = __builtin_amdgcn_ds_swizzle(x, 0x101F);                    // xor4, and=0x1F
    } else if constexpr (LM == 8) {
        x = __builtin_amdgcn_update_dpp(x, x, 0x128, 0xF, 0xF, true);  // ROW_ROR:8 == xor8
    } else if constexpr (LM == 16) {
#if __has_builtin(__builtin_amdgcn_permlane16_swap)
        auto r = __builtin_amdgcn_permlane16_swap(x, x, false, false);
        // ret[0] = rows [r0,r0,r2,r2], ret[1] = rows [r1,r1,r3,r3]; want [r1,r0,r3,r2]
        x = (lane & 16) ? r[0] : r[1];
#else
        return __shfl_xor(v, 16, 64);
#endif
    } else {  // LM == 32
#if __has_builtin(__builtin_amdgcn_permlane32_swap)
        auto r = __builtin_amdgcn_permlane32_swap(x, x, false, false);
        // ret[0] = [lo,lo], ret[1] = [hi,hi]; want [hi,lo]
        x = (lane & 32) ? r[0] : r[1];
#else
        return __shfl_xor(v, 32, 64);
#endif
    }
    return __int_as_float(x);
}

__device__ __forceinline__ float wave_sum(float v, int lane) {
    v += lxor<32>(v, lane);
    v += lxor<16>(v, lane);
    v += lxor<8>(v, lane);
    v += lxor<4>(v, lane);
    v += lxor<2>(v, lane);
    v += lxor<1>(v, lane);
    return v;
}

// State layout: amplitude index i (9 bits) -> lane = i>>3 (bits 8..3), reg r = i&7 (bits 2..0).
// Qubit j <-> state bit BJ = 8-j.

template<int BJ, bool RX>
__device__ __forceinline__ void rot(float2 st[8], float c, float s, int lane) {
    if constexpr (BJ >= 3) {
        constexpr int lm = 1 << (BJ - 3);
        const float sgn = (lane & lm) ? s : -s;   // RY only
#pragma unroll
        for (int r = 0; r < 8; ++r) {
            float px = lxor<lm>(st[r].x, lane);
            float py = lxor<lm>(st[r].y, lane);
            float nx, ny;
            if constexpr (RX) { nx = c * st[r].x + s * py;   ny = c * st[r].y - s * px; }
            else              { nx = c * st[r].x + sgn * px; ny = c * st[r].y + sgn * py; }
            st[r].x = nx; st[r].y = ny;
        }
    } else {
        constexpr int M = 1 << BJ;
#pragma unroll
        for (int r = 0; r < 8; ++r) {
            if ((r & M) == 0) {
                float2 a = st[r], b = st[r + M];
                if constexpr (RX) {
                    st[r].x     = c * a.x + s * b.y;  st[r].y     = c * a.y - s * b.x;
                    st[r + M].x = c * b.x + s * a.y;  st[r + M].y = c * b.y - s * a.x;
                } else {
                    st[r].x     = c * a.x - s * b.x;  st[r].y     = c * a.y - s * b.y;
                    st[r + M].x = s * a.x + c * b.x;  st[r + M].y = s * a.y + c * b.y;
                }
            }
        }
    }
}

// CNOT with control state-bit CB, target state-bit TB.
template<int CB, int TB>
__device__ __forceinline__ void cnot(float2 st[8], int lane) {
    if constexpr (CB >= 3 && TB >= 3) {
        constexpr int tlm = 1 << (TB - 3);
        const bool ctrl = (lane >> (CB - 3)) & 1;
#pragma unroll
        for (int r = 0; r < 8; ++r) {
            float px = lxor<tlm>(st[r].x, lane);
            float py = lxor<tlm>(st[r].y, lane);
            if (ctrl) { st[r].x = px; st[r].y = py; }
        }
    } else if constexpr (CB >= 3 && TB < 3) {
        constexpr int M = 1 << TB;
        const bool ctrl = (lane >> (CB - 3)) & 1;
#pragma unroll
        for (int r = 0; r < 8; ++r) {
            if ((r & M) == 0) {
                float2 a = st[r], b = st[r + M];
                st[r].x     = ctrl ? b.x : a.x;  st[r].y     = ctrl ? b.y : a.y;
                st[r + M].x = ctrl ? a.x : b.x;  st[r + M].y = ctrl ? a.y : b.y;
            }
        }
    } else if constexpr (CB < 3 && TB < 3) {
        constexpr int CM = 1 << CB, M = 1 << TB;
#pragma unroll
        for (int r = 0; r < 8; ++r) {
            if ((r & CM) && !(r & M)) { float2 t = st[r]; st[r] = st[r + M]; st[r + M] = t; }
        }
    } else {  // CB < 3, TB >= 3
        constexpr int CM = 1 << CB;
        constexpr int tlm = 1 << (TB - 3);
#pragma unroll
        for (int r = 0; r < 8; ++r) {
            if (r & CM) {
                st[r].x = lxor<tlm>(st[r].x, lane);
                st[r].y = lxor<tlm>(st[r].y, lane);
            }
        }
    }
}

// CNOT ring: (control j, target (j+1)%9) -> state bits (8,7)(7,6)...(1,0)(0,8)
__device__ __forceinline__ void ring(float2 st[8], int lane) {
    cnot<8, 7>(st, lane); cnot<7, 6>(st, lane); cnot<6, 5>(st, lane);
    cnot<5, 4>(st, lane); cnot<4, 3>(st, lane); cnot<3, 2>(st, lane);
    cnot<2, 1>(st, lane); cnot<1, 0>(st, lane); cnot<0, 8>(st, lane);
}

#define INITQ(j) { float2 c0 = cs[2 * (j)], c1 = cs[2 * (j) + 1];      \
                   rot<8 - (j), true >(st, c0.x, c0.y, lane);          \
                   rot<8 - (j), false>(st, c1.x, c1.y, lane); }

__device__ __forceinline__ void run_circuit(float2 st[8], const float2* cs, int layers, int lane) {
    INITQ(0) INITQ(1) INITQ(2) INITQ(3) INITQ(4)
    INITQ(5) INITQ(6) INITQ(7) INITQ(8)
    const float2* p = cs + 18;
#pragma unroll 1
    for (int L = 0; L < layers; ++L) {
        ring(st, lane);
        { float2 cc = p[0]; rot<8, false>(st, cc.x, cc.y, lane); }
        { float2 cc = p[1]; rot<7, false>(st, cc.x, cc.y, lane); }
        { float2 cc = p[2]; rot<6, false>(st, cc.x, cc.y, lane); }
        { float2 cc = p[3]; rot<5, false>(st, cc.x, cc.y, lane); }
        { float2 cc = p[4]; rot<4, false>(st, cc.x, cc.y, lane); }
        { float2 cc = p[5]; rot<3, false>(st, cc.x, cc.y, lane); }
        { float2 cc = p[6]; rot<2, false>(st, cc.x, cc.y, lane); }
        { float2 cc = p[7]; rot<1, false>(st, cc.x, cc.y, lane); }
        { float2 cc = p[8]; rot<0, false>(st, cc.x, cc.y, lane); }
        p += 9;
    }
}

// <Z>, <X>, <Y> on qubit with state-bit BJ.
template<int BJ>
__device__ __forceinline__ void expv(const float2 st[8], int lane, float& ez, float& ex, float& ey) {
    ez = ex = ey = 0.f;
    if constexpr (BJ >= 3) {
        constexpr int lm = 1 << (BJ - 3);
        const float sgn = (lane & lm) ? -1.f : 1.f;
#pragma unroll
        for (int r = 0; r < 8; ++r) {
            float px = lxor<lm>(st[r].x, lane);
            float py = lxor<lm>(st[r].y, lane);
            ez += sgn * (st[r].x * st[r].x + st[r].y * st[r].y);
            ex += st[r].x * px + st[r].y * py;
            ey += sgn * (st[r].x * py - st[r].y * px);
        }
    } else {
        constexpr int M = 1 << BJ;
#pragma unroll
        for (int r = 0; r < 8; ++r) {
            if ((r & M) == 0) {
                float2 a = st[r], b = st[r + M];
                ez += (a.x * a.x + a.y * a.y) - (b.x * b.x + b.y * b.y);
                ex += 2.f * (a.x * b.x + a.y * b.y);
                ey += 2.f * (a.x * b.y - a.y * b.x);
            }
        }
    }
    ez = wave_sum(ez, lane); ex = wave_sum(ex, lane); ey = wave_sum(ey, lane);
}

__global__ __launch_bounds__(64) void sim_kernel(
    const float* __restrict__ inp, const float* __restrict__ wq,
    const float* __restrict__ wk,  const float* __restrict__ wv,
    float* __restrict__ outQ, float* __restrict__ outK, float* __restrict__ outV)
{
    __shared__ float2 cs[54 + 270];   // {cos(t/2), sin(t/2)} per angle

    const int fi   = blockIdx.x;      // flat = s*B + b
    const int lane = threadIdx.x;
    const int b = fi % B_DIM, s = fi / B_DIM;
    const float* x = inp + ((size_t)b * S_DIM + s) * D_DIM;

    for (int k = lane; k < 324; k += 64) {
        float ang = (k < 54)  ? x[k]
                  : (k < 144) ? wq[k - 54]
                  : (k < 234) ? wk[k - 144]
                              : wv[k - 234];
        float sn, cn; sincosf(0.5f * ang, &sn, &cn);
        cs[k] = make_float2(cn, sn);
    }
    __syncthreads();

    float2 st[8], ck[8];
#pragma unroll
    for (int r = 0; r < 8; ++r) st[r] = make_float2(0.f, 0.f);
    if (lane == 0) st[0].x = 1.f;

    run_circuit(st, cs, DENC, lane);
#pragma unroll
    for (int r = 0; r < 8; ++r) ck[r] = st[r];

    // ---- Q ----
    run_circuit(st, cs + 54, DVAR, lane);
    {
        float p = 0.f;
#pragma unroll
        for (int r = 0; r < 8; ++r) p += st[r].x * st[r].x + st[r].y * st[r].y;
        p = (lane & 32) ? -p : p;     // qubit 0 = state bit 8 = lane bit 5
        p = wave_sum(p, lane);
        if (lane == 0) outQ[fi] = p;
    }

    // ---- K ----
#pragma unroll
    for (int r = 0; r < 8; ++r) st[r] = ck[r];
    run_circuit(st, cs + 144, DVAR, lane);
    {
        float p = 0.f;
#pragma unroll
        for (int r = 0; r < 8; ++r) p += st[r].x * st[r].x + st[r].y * st[r].y;
        p = (lane & 32) ? -p : p;
        p = wave_sum(p, lane);
        if (lane == 0) outK[fi] = p;
    }

    // ---- V ----
#pragma unroll
    for (int r = 0; r < 8; ++r) st[r] = ck[r];
    run_circuit(st, cs + 234, DVAR, lane);
    {
        float* vrow = outV + (size_t)fi * D_DIM;
#define EXPQ(q) { float ez, ex, ey; expv<8 - (q)>(st, lane, ez, ex, ey);            \
                  if (lane == 0) { vrow[(q)] = ez; vrow[9 + (q)] = ex;              \
                                   vrow[18 + (q)] = ey; vrow[27 + (q)] = ez;        \
                                   vrow[36 + (q)] = ex; vrow[45 + (q)] = ey; } }
        EXPQ(0) EXPQ(1) EXPQ(2) EXPQ(3) EXPQ(4)
        EXPQ(5) EXPQ(6) EXPQ(7) EXPQ(8)
#undef EXPQ
    }
}

__global__ __launch_bounds__(64) void attn_kernel(
    const float* __restrict__ inp, const float* __restrict__ Q,
    const float* __restrict__ K,   const float* __restrict__ V,
    float* __restrict__ out)
{
    __shared__ float w[S_DIM];
    const int bi = blockIdx.x;         // b*S + i
    const int b  = bi / S_DIM;
    const int i  = bi % S_DIM;
    const int t  = threadIdx.x;

    const float q = Q[i * B_DIM + b];
    for (int j = t; j < S_DIM; j += 64) {
        float diff = q - K[j * B_DIM + b];
        w[j] = expf(-diff * diff);
    }
    __syncthreads();

    float ps = 0.f;
    for (int j = t; j < S_DIM; j += 64) ps += w[j];
    ps = wave_sum(ps, t);
    const float inv = 1.f / ps;

    if (t < D_DIM) {
        float acc = 0.f;
        for (int j = 0; j < S_DIM; ++j)
            acc += w[j] * V[(size_t)(j * B_DIM + b) * D_DIM + t];
        size_t o = (size_t)bi * D_DIM + t;
        out[o] = inp[o] + acc * inv;
    }
}

extern "C" void kernel_launch(void* const* d_in, const int* in_sizes, int n_in,
                              void* d_out, int out_size, void* d_ws, size_t ws_size,
                              hipStream_t stream)
{
    (void)in_sizes; (void)n_in; (void)out_size; (void)ws_size;
    const float* inp = (const float*)d_in[0];
    const float* wq  = (const float*)d_in[1];
    const float* wk  = (const float*)d_in[2];
    const float* wv  = (const float*)d_in[3];
    float* outp = (float*)d_out;

    float* Qw = (float*)d_ws;
    float* Kw = Qw + NFLAT;
    float* Vw = Kw + NFLAT;

    sim_kernel<<<NFLAT, 64, 0, stream>>>(inp, wq, wk, wv, Qw, Kw, Vw);
    attn_kernel<<<NFLAT, 64, 0, stream>>>(inp, Qw, Kw, Vw, outp);
}

// Round 5
// 155.389 us; speedup vs baseline: 3.0371x; 1.3397x over previous
//
#include <hip/hip_runtime.h>
#include <math.h>

#define NQ     9
#define B_DIM  48
#define S_DIM  96
#define D_DIM  54
#define DENC   4
#define DVAR   8
#define NFLAT  (B_DIM * S_DIM)   // 4608

typedef float f32x2 __attribute__((ext_vector_type(2)));

// Masked DPP: lanes enabled by row_mask/bank_mask get DPP-selected src; others keep old.
template<int CTRL, int RM, int BM>
__device__ __forceinline__ float mdpp(float old_, float src) {
    return __int_as_float(__builtin_amdgcn_update_dpp(
        __float_as_int(old_), __float_as_int(src), CTRL, RM, BM, false));
}

// Unconditional lane-xor: DPP for 1,2,8; ds_swizzle for 4,16; permlane32_swap for 32.
template<int LM>
__device__ __forceinline__ float lx(float v, int lane) {
    int x = __float_as_int(v);
    if constexpr (LM == 1)       x = __builtin_amdgcn_update_dpp(x, x, 0xB1, 0xF, 0xF, true);  // quad[1,0,3,2]
    else if constexpr (LM == 2)  x = __builtin_amdgcn_update_dpp(x, x, 0x4E, 0xF, 0xF, true);  // quad[2,3,0,1]
    else if constexpr (LM == 4)  x = __builtin_amdgcn_ds_swizzle(x, 0x101F);                   // xor4
    else if constexpr (LM == 8)  x = __builtin_amdgcn_update_dpp(x, x, 0x128, 0xF, 0xF, true); // ROW_ROR:8
    else if constexpr (LM == 16) x = __builtin_amdgcn_ds_swizzle(x, 0x401F);                   // xor16
    else {
        auto r = __builtin_amdgcn_permlane32_swap(x, x, false, false);
        // ret[0] = [lo,lo], ret[1] = [hi,hi]; want [hi,lo]
        x = (lane & 32) ? r[0] : r[1];
    }
    return __int_as_float(x);
}

__device__ __forceinline__ float wave_sum(float v, int lane) {
    v += lx<32>(v, lane);
    v += lx<16>(v, lane);
    v += lx<8>(v, lane);
    v += lx<4>(v, lane);
    v += lx<2>(v, lane);
    v += lx<1>(v, lane);
    return v;
}

// State layout: amp index i (9 bits) -> lane = i>>3 (bits 8..3), reg r = i&7 (bits 2..0).
// Qubit j <-> state bit BJ = 8-j.

// CNOT ring (control j, target (j+1)%9): state-bit pairs (8,7)(7,6)...(1,0)(0,8).
__device__ __forceinline__ void ring(f32x2 st[8], int lane) {
    const bool c5 = (lane & 32) != 0;
    // (8,7): ctrl lane5, tgt xor16: swizzle + cndmask
#pragma unroll
    for (int r = 0; r < 8; ++r) {
        float nx = lx<16>(st[r].x, lane), ny = lx<16>(st[r].y, lane);
        st[r].x = c5 ? nx : st[r].x;
        st[r].y = c5 ? ny : st[r].y;
    }
    // (7,6): ctrl lane4 (rows 1,3), tgt xor8: masked ROW_ROR:8
#pragma unroll
    for (int r = 0; r < 8; ++r) {
        st[r].x = mdpp<0x128, 0xA, 0xF>(st[r].x, st[r].x);
        st[r].y = mdpp<0x128, 0xA, 0xF>(st[r].y, st[r].y);
    }
    // (6,5): ctrl lane3 (banks 2,3), tgt xor4: bank3<-shl4 from orig, bank2<-shr4 from orig
#pragma unroll
    for (int r = 0; r < 8; ++r) {
        float tx = st[r].x, ty = st[r].y;
        float ax = mdpp<0x104, 0xF, 0x8>(tx, tx);   // ROW_SHL:4 into bank 3
        st[r].x  = mdpp<0x114, 0xF, 0x4>(ax, tx);   // ROW_SHR:4 into bank 2 (src = original)
        float ay = mdpp<0x104, 0xF, 0x8>(ty, ty);
        st[r].y  = mdpp<0x114, 0xF, 0x4>(ay, ty);
    }
    // (5,4): ctrl lane2 (banks 1,3), tgt xor2: masked quad_perm[2,3,0,1]
#pragma unroll
    for (int r = 0; r < 8; ++r) {
        st[r].x = mdpp<0x4E, 0xF, 0xA>(st[r].x, st[r].x);
        st[r].y = mdpp<0x4E, 0xF, 0xA>(st[r].y, st[r].y);
    }
    // (4,3): ctrl lane1, tgt xor1: quad_perm[0,1,3,2] = 0xB4 (conditional swap in one op)
#pragma unroll
    for (int r = 0; r < 8; ++r) {
        st[r].x = mdpp<0xB4, 0xF, 0xF>(st[r].x, st[r].x);
        st[r].y = mdpp<0xB4, 0xF, 0xF>(st[r].y, st[r].y);
    }
    // (3,2): ctrl lane0, tgt reg bit2
    {
        const bool c0 = (lane & 1) != 0;
#pragma unroll
        for (int r = 0; r < 4; ++r) {
            f32x2 a = st[r], b = st[r + 4];
            st[r]     = c0 ? b : a;
            st[r + 4] = c0 ? a : b;
        }
    }
    // (2,1): regs with bit2: r <-> r^2 (rename)
    { f32x2 t = st[4]; st[4] = st[6]; st[6] = t; }
    { f32x2 t = st[5]; st[5] = st[7]; st[7] = t; }
    // (1,0): regs with bit1: r <-> r^1 (rename)
    { f32x2 t = st[2]; st[2] = st[3]; st[3] = t; }
    { f32x2 t = st[6]; st[6] = st[7]; st[7] = t; }
    // (0,8): odd regs: xor32
#pragma unroll
    for (int r = 1; r < 8; r += 2) {
        st[r].x = lx<32>(st[r].x, lane);
        st[r].y = lx<32>(st[r].y, lane);
    }
}

template<int BJ>
__device__ __forceinline__ void rot_ry(f32x2 st[8], float c, float s, int lane) {
    const f32x2 c2 = {c, c};
    if constexpr (BJ >= 3) {
        constexpr int lm = 1 << (BJ - 3);
        const float sg = (lane & lm) ? s : -s;
        const f32x2 sg2 = {sg, sg};
#pragma unroll
        for (int r = 0; r < 8; ++r) {
            f32x2 p = { lx<lm>(st[r].x, lane), lx<lm>(st[r].y, lane) };
            st[r] = st[r] * c2 + p * sg2;           // v_pk_mul/v_pk_fma
        }
    } else {
        constexpr int M = 1 << BJ;
        const f32x2 s2 = {s, s}, ns2 = {-s, -s};
#pragma unroll
        for (int r = 0; r < 8; ++r) {
            if ((r & M) == 0) {
                f32x2 a = st[r], b = st[r + M];
                st[r]     = a * c2 + b * ns2;
                st[r + M] = b * c2 + a * s2;
            }
        }
    }
}

template<int BJ>
__device__ __forceinline__ void rot_rx(f32x2 st[8], float c, float s, int lane) {
    if constexpr (BJ >= 3) {
        constexpr int lm = 1 << (BJ - 3);
#pragma unroll
        for (int r = 0; r < 8; ++r) {
            float px = lx<lm>(st[r].x, lane), py = lx<lm>(st[r].y, lane);
            float nx = fmaf(s, py, c * st[r].x);
            float ny = fmaf(-s, px, c * st[r].y);
            st[r].x = nx; st[r].y = ny;
        }
    } else {
        constexpr int M = 1 << BJ;
#pragma unroll
        for (int r = 0; r < 8; ++r) {
            if ((r & M) == 0) {
                f32x2 a = st[r], b = st[r + M];
                st[r].x     = fmaf(s, b.y, c * a.x);
                st[r].y     = fmaf(-s, b.x, c * a.y);
                st[r + M].x = fmaf(s, a.y, c * b.x);
                st[r + M].y = fmaf(-s, a.x, c * b.y);
            }
        }
    }
}

#define INITQ(j) { f32x2 c0 = cs[2 * (j)], c1 = cs[2 * (j) + 1];      \
                   rot_rx<8 - (j)>(st, c0.x, c0.y, lane);             \
                   rot_ry<8 - (j)>(st, c1.x, c1.y, lane); }

__device__ __forceinline__ void run_circuit(f32x2 st[8], const f32x2* cs, int layers, int lane) {
    INITQ(0) INITQ(1) INITQ(2) INITQ(3) INITQ(4)
    INITQ(5) INITQ(6) INITQ(7) INITQ(8)
    const f32x2* p = cs + 18;
#pragma unroll 1
    for (int L = 0; L < layers; ++L) {
        ring(st, lane);
        { f32x2 cc = p[0]; rot_ry<8>(st, cc.x, cc.y, lane); }
        { f32x2 cc = p[1]; rot_ry<7>(st, cc.x, cc.y, lane); }
        { f32x2 cc = p[2]; rot_ry<6>(st, cc.x, cc.y, lane); }
        { f32x2 cc = p[3]; rot_ry<5>(st, cc.x, cc.y, lane); }
        { f32x2 cc = p[4]; rot_ry<4>(st, cc.x, cc.y, lane); }
        { f32x2 cc = p[5]; rot_ry<3>(st, cc.x, cc.y, lane); }
        { f32x2 cc = p[6]; rot_ry<2>(st, cc.x, cc.y, lane); }
        { f32x2 cc = p[7]; rot_ry<1>(st, cc.x, cc.y, lane); }
        { f32x2 cc = p[8]; rot_ry<0>(st, cc.x, cc.y, lane); }
        p += 9;
    }
}

// <Z>, <X>, <Y> on qubit with state-bit BJ.
template<int BJ>
__device__ __forceinline__ void expv(const f32x2 st[8], int lane, float& ez, float& ex, float& ey) {
    ez = ex = ey = 0.f;
    if constexpr (BJ >= 3) {
        constexpr int lm = 1 << (BJ - 3);
        const float sgn = (lane & lm) ? -1.f : 1.f;
#pragma unroll
        for (int r = 0; r < 8; ++r) {
            float px = lx<lm>(st[r].x, lane);
            float py = lx<lm>(st[r].y, lane);
            ez += sgn * (st[r].x * st[r].x + st[r].y * st[r].y);
            ex += st[r].x * px + st[r].y * py;
            ey += sgn * (st[r].x * py - st[r].y * px);
        }
    } else {
        constexpr int M = 1 << BJ;
#pragma unroll
        for (int r = 0; r < 8; ++r) {
            if ((r & M) == 0) {
                f32x2 a = st[r], b = st[r + M];
                ez += (a.x * a.x + a.y * a.y) - (b.x * b.x + b.y * b.y);
                ex += 2.f * (a.x * b.x + a.y * b.y);
                ey += 2.f * (a.x * b.y - a.y * b.x);
            }
        }
    }
    ez = wave_sum(ez, lane); ex = wave_sum(ex, lane); ey = wave_sum(ey, lane);
}

__global__ __launch_bounds__(256) void sim_kernel(
    const float* __restrict__ inp, const float* __restrict__ wq,
    const float* __restrict__ wk,  const float* __restrict__ wv,
    float* __restrict__ outQ, float* __restrict__ outK, float* __restrict__ outV)
{
    __shared__ f32x2 cs_all[4][54 + 270];   // per-wave {cos(t/2), sin(t/2)} tables

    const int warp = threadIdx.x >> 6;
    const int lane = threadIdx.x & 63;
    const int fi   = blockIdx.x * 4 + warp; // flat = s*B + b
    const int b = fi % B_DIM, s = fi / B_DIM;
    const float* x = inp + ((size_t)b * S_DIM + s) * D_DIM;
    f32x2* cs = cs_all[warp];

    for (int k = lane; k < 324; k += 64) {
        float ang = (k < 54)  ? x[k]
                  : (k < 144) ? wq[k - 54]
                  : (k < 234) ? wk[k - 144]
                              : wv[k - 234];
        float sn, cn; sincosf(0.5f * ang, &sn, &cn);
        f32x2 v = {cn, sn};
        cs[k] = v;
    }
    // wave-local LDS use only: no __syncthreads needed

    f32x2 st[8], ck[8];
#pragma unroll
    for (int r = 0; r < 8; ++r) { f32x2 z = {0.f, 0.f}; st[r] = z; }
    if (lane == 0) st[0].x = 1.f;

    run_circuit(st, cs, DENC, lane);
#pragma unroll
    for (int r = 0; r < 8; ++r) ck[r] = st[r];

    // ---- Q ----
    run_circuit(st, cs + 54, DVAR, lane);
    {
        float p = 0.f;
#pragma unroll
        for (int r = 0; r < 8; ++r) p += st[r].x * st[r].x + st[r].y * st[r].y;
        p = (lane & 32) ? -p : p;     // qubit 0 = state bit 8 = lane bit 5
        p = wave_sum(p, lane);
        if (lane == 0) outQ[fi] = p;
    }

    // ---- K ----
#pragma unroll
    for (int r = 0; r < 8; ++r) st[r] = ck[r];
    run_circuit(st, cs + 144, DVAR, lane);
    {
        float p = 0.f;
#pragma unroll
        for (int r = 0; r < 8; ++r) p += st[r].x * st[r].x + st[r].y * st[r].y;
        p = (lane & 32) ? -p : p;
        p = wave_sum(p, lane);
        if (lane == 0) outK[fi] = p;
    }

    // ---- V ----
#pragma unroll
    for (int r = 0; r < 8; ++r) st[r] = ck[r];
    run_circuit(st, cs + 234, DVAR, lane);
    {
        float* vrow = outV + (size_t)fi * D_DIM;
#define EXPQ(q) { float ez, ex, ey; expv<8 - (q)>(st, lane, ez, ex, ey);            \
                  if (lane == 0) { vrow[(q)] = ez; vrow[9 + (q)] = ex;              \
                                   vrow[18 + (q)] = ey; vrow[27 + (q)] = ez;        \
                                   vrow[36 + (q)] = ex; vrow[45 + (q)] = ey; } }
        EXPQ(0) EXPQ(1) EXPQ(2) EXPQ(3) EXPQ(4)
        EXPQ(5) EXPQ(6) EXPQ(7) EXPQ(8)
#undef EXPQ
    }
}

__global__ __launch_bounds__(256) void attn_kernel(
    const float* __restrict__ inp, const float* __restrict__ Q,
    const float* __restrict__ K,   const float* __restrict__ V,
    float* __restrict__ out)
{
    __shared__ float w4[4][S_DIM];
    const int warp = threadIdx.x >> 6;
    const int t    = threadIdx.x & 63;
    const int bi   = blockIdx.x * 4 + warp;   // b*S + i
    const int b    = bi / S_DIM;
    const int i    = bi % S_DIM;
    float* w = w4[warp];

    const float q = Q[i * B_DIM + b];
    float e0, e1 = 0.f;
    {
        float d0 = q - K[t * B_DIM + b];
        e0 = expf(-d0 * d0);
        w[t] = e0;
        if (t < S_DIM - 64) {
            float d1 = q - K[(t + 64) * B_DIM + b];
            e1 = expf(-d1 * d1);
            w[t + 64] = e1;
        }
    }
    float ps = wave_sum(e0 + e1, t);
    const float inv = 1.f / ps;

    if (t < D_DIM) {
        float acc = 0.f;
        for (int j = 0; j < S_DIM; ++j)
            acc += w[j] * V[(size_t)(j * B_DIM + b) * D_DIM + t];
        size_t o = (size_t)bi * D_DIM + t;
        out[o] = inp[o] + acc * inv;
    }
}

extern "C" void kernel_launch(void* const* d_in, const int* in_sizes, int n_in,
                              void* d_out, int out_size, void* d_ws, size_t ws_size,
                              hipStream_t stream)
{
    (void)in_sizes; (void)n_in; (void)out_size; (void)ws_size;
    const float* inp = (const float*)d_in[0];
    const float* wq  = (const float*)d_in[1];
    const float* wk  = (const float*)d_in[2];
    const float* wv  = (const float*)d_in[3];
    float* outp = (float*)d_out;

    float* Qw = (float*)d_ws;
    float* Kw = Qw + NFLAT;
    float* Vw = Kw + NFLAT;

    sim_kernel<<<NFLAT / 4, 256, 0, stream>>>(inp, wq, wk, wv, Qw, Kw, Vw);
    attn_kernel<<<NFLAT / 4, 256, 0, stream>>>(inp, Qw, Kw, Vw, outp);
}

// Round 7
// 154.115 us; speedup vs baseline: 3.0622x; 1.0083x over previous
//
#include <hip/hip_runtime.h>
#include <math.h>

#define NQ     9
#define B_DIM  48
#define S_DIM  96
#define D_DIM  54
#define DENC   4
#define DVAR   8
#define NFLAT  (B_DIM * S_DIM)   // 4608

typedef float f32x2 __attribute__((ext_vector_type(2)));

// Masked DPP: lanes enabled by row_mask/bank_mask get DPP-selected src; others keep old.
template<int CTRL, int RM, int BM>
__device__ __forceinline__ float mdpp(float old_, float src) {
    return __int_as_float(__builtin_amdgcn_update_dpp(
        __float_as_int(old_), __float_as_int(src), CTRL, RM, BM, false));
}

// Lane-xor primitives — EXACTLY the R5 hardware-validated set.
// 1,2: quad_perm DPP; 4: ds_swizzle; 8: ROW_ROR:8 DPP; 16: ds_swizzle; 32: permlane32_swap.
template<int LM>
__device__ __forceinline__ float lx(float v, int lane) {
    int x = __float_as_int(v);
    if constexpr (LM == 1)       x = __builtin_amdgcn_update_dpp(x, x, 0xB1, 0xF, 0xF, true);  // quad[1,0,3,2]
    else if constexpr (LM == 2)  x = __builtin_amdgcn_update_dpp(x, x, 0x4E, 0xF, 0xF, true);  // quad[2,3,0,1]
    else if constexpr (LM == 4)  x = __builtin_amdgcn_ds_swizzle(x, 0x101F);                   // xor4
    else if constexpr (LM == 8)  x = __builtin_amdgcn_update_dpp(x, x, 0x128, 0xF, 0xF, true); // ROW_ROR:8
    else if constexpr (LM == 16) x = __builtin_amdgcn_ds_swizzle(x, 0x401F);                   // xor16
    else {
        auto r = __builtin_amdgcn_permlane32_swap(x, x, false, false);
        // ret[0] = [lo,lo], ret[1] = [hi,hi]; want [hi,lo]
        x = (lane & 32) ? r[0] : r[1];
    }
    return __int_as_float(x);
}

__device__ __forceinline__ float wave_sum(float v, int lane) {
    v += lx<32>(v, lane);
    v += lx<16>(v, lane);
    v += lx<8>(v, lane);
    v += lx<4>(v, lane);
    v += lx<2>(v, lane);
    v += lx<1>(v, lane);
    return v;
}

// State layout: amp index i (9 bits) -> lane = i>>3 (bits 8..3), reg r = i&7 (bits 2..0).
// Qubit j <-> state bit BJ = 8-j.

// CNOT ring (control j, target (j+1)%9): state-bit pairs (8,7)(7,6)...(1,0)(0,8).
__device__ __forceinline__ void ring(f32x2 st[8], int lane) {
    const bool c5 = (lane & 32) != 0;
    // (8,7): ctrl lane5, tgt xor16
#pragma unroll
    for (int r = 0; r < 8; ++r) {
        float nx = lx<16>(st[r].x, lane), ny = lx<16>(st[r].y, lane);
        st[r].x = c5 ? nx : st[r].x;
        st[r].y = c5 ? ny : st[r].y;
    }
    // (7,6): ctrl lane4 (rows 1,3), tgt xor8: masked ROW_ROR:8
#pragma unroll
    for (int r = 0; r < 8; ++r) {
        st[r].x = mdpp<0x128, 0xA, 0xF>(st[r].x, st[r].x);
        st[r].y = mdpp<0x128, 0xA, 0xF>(st[r].y, st[r].y);
    }
    // (6,5): ctrl lane3 (banks 2,3), tgt xor4: bank3<-shl4, bank2<-shr4 from orig
#pragma unroll
    for (int r = 0; r < 8; ++r) {
        float tx = st[r].x, ty = st[r].y;
        float ax = mdpp<0x104, 0xF, 0x8>(tx, tx);   // ROW_SHL:4 into bank 3
        st[r].x  = mdpp<0x114, 0xF, 0x4>(ax, tx);   // ROW_SHR:4 into bank 2 (src = original)
        float ay = mdpp<0x104, 0xF, 0x8>(ty, ty);
        st[r].y  = mdpp<0x114, 0xF, 0x4>(ay, ty);
    }
    // (5,4): ctrl lane2 (banks 1,3), tgt xor2: masked quad_perm[2,3,0,1]
#pragma unroll
    for (int r = 0; r < 8; ++r) {
        st[r].x = mdpp<0x4E, 0xF, 0xA>(st[r].x, st[r].x);
        st[r].y = mdpp<0x4E, 0xF, 0xA>(st[r].y, st[r].y);
    }
    // (4,3): ctrl lane1, tgt xor1: quad_perm[0,1,3,2] = 0xB4
#pragma unroll
    for (int r = 0; r < 8; ++r) {
        st[r].x = mdpp<0xB4, 0xF, 0xF>(st[r].x, st[r].x);
        st[r].y = mdpp<0xB4, 0xF, 0xF>(st[r].y, st[r].y);
    }
    // (3,2): ctrl lane0, tgt reg bit2
    {
        const bool c0 = (lane & 1) != 0;
#pragma unroll
        for (int r = 0; r < 4; ++r) {
            f32x2 a = st[r], b = st[r + 4];
            st[r]     = c0 ? b : a;
            st[r + 4] = c0 ? a : b;
        }
    }
    // (2,1): regs with bit2: r <-> r^2 (rename)
    { f32x2 t = st[4]; st[4] = st[6]; st[6] = t; }
    { f32x2 t = st[5]; st[5] = st[7]; st[7] = t; }
    // (1,0): regs with bit1: r <-> r^1 (rename)
    { f32x2 t = st[2]; st[2] = st[3]; st[3] = t; }
    { f32x2 t = st[6]; st[6] = st[7]; st[7] = t; }
    // (0,8): odd regs: xor32
#pragma unroll
    for (int r = 1; r < 8; r += 2) {
        st[r].x = lx<32>(st[r].x, lane);
        st[r].y = lx<32>(st[r].y, lane);
    }
}

template<int BJ>
__device__ __forceinline__ void rot_ry(f32x2 st[8], float c, float s, int lane) {
    const f32x2 c2 = {c, c};
    if constexpr (BJ >= 3) {
        constexpr int lm = 1 << (BJ - 3);
        const float sg = (lane & lm) ? s : -s;
        const f32x2 sg2 = {sg, sg};
#pragma unroll
        for (int r = 0; r < 8; ++r) {
            f32x2 p = { lx<lm>(st[r].x, lane), lx<lm>(st[r].y, lane) };
            st[r] = st[r] * c2 + p * sg2;
        }
    } else {
        constexpr int M = 1 << BJ;
        const f32x2 s2 = {s, s}, ns2 = {-s, -s};
#pragma unroll
        for (int r = 0; r < 8; ++r) {
            if ((r & M) == 0) {
                f32x2 a = st[r], b = st[r + M];
                st[r]     = a * c2 + b * ns2;
                st[r + M] = b * c2 + a * s2;
            }
        }
    }
}

template<int BJ>
__device__ __forceinline__ void rot_rx(f32x2 st[8], float c, float s, int lane) {
    if constexpr (BJ >= 3) {
        constexpr int lm = 1 << (BJ - 3);
#pragma unroll
        for (int r = 0; r < 8; ++r) {
            float px = lx<lm>(st[r].x, lane), py = lx<lm>(st[r].y, lane);
            float nx = fmaf(s, py, c * st[r].x);
            float ny = fmaf(-s, px, c * st[r].y);
            st[r].x = nx; st[r].y = ny;
        }
    } else {
        constexpr int M = 1 << BJ;
#pragma unroll
        for (int r = 0; r < 8; ++r) {
            if ((r & M) == 0) {
                f32x2 a = st[r], b = st[r + M];
                st[r].x     = fmaf(s, b.y, c * a.x);
                st[r].y     = fmaf(-s, b.x, c * a.y);
                st[r + M].x = fmaf(s, a.y, c * b.x);
                st[r + M].y = fmaf(-s, a.x, c * b.y);
            }
        }
    }
}

#define INITQ(j) { f32x2 c0 = cs[2 * (j)], c1 = cs[2 * (j) + 1];      \
                   rot_rx<8 - (j)>(st, c0.x, c0.y, lane);             \
                   rot_ry<8 - (j)>(st, c1.x, c1.y, lane); }

// Single-stream circuit (encoding phase) — R5 form.
__device__ __forceinline__ void run_circuit(f32x2 st[8], const f32x2* cs, int layers, int lane) {
    INITQ(0) INITQ(1) INITQ(2) INITQ(3) INITQ(4)
    INITQ(5) INITQ(6) INITQ(7) INITQ(8)
    const f32x2* p = cs + 18;
#pragma unroll 1
    for (int L = 0; L < layers; ++L) {
        ring(st, lane);
        { f32x2 cc = p[0]; rot_ry<8>(st, cc.x, cc.y, lane); }
        { f32x2 cc = p[1]; rot_ry<7>(st, cc.x, cc.y, lane); }
        { f32x2 cc = p[2]; rot_ry<6>(st, cc.x, cc.y, lane); }
        { f32x2 cc = p[3]; rot_ry<5>(st, cc.x, cc.y, lane); }
        { f32x2 cc = p[4]; rot_ry<4>(st, cc.x, cc.y, lane); }
        { f32x2 cc = p[5]; rot_ry<3>(st, cc.x, cc.y, lane); }
        { f32x2 cc = p[6]; rot_ry<2>(st, cc.x, cc.y, lane); }
        { f32x2 cc = p[7]; rot_ry<1>(st, cc.x, cc.y, lane); }
        { f32x2 cc = p[8]; rot_ry<0>(st, cc.x, cc.y, lane); }
        p += 9;
    }
}

// Three independent variational circuits (Q,K,V) interleaved for 3x ILP.
__device__ __forceinline__ void run3(f32x2 sq[8], f32x2 sk[8], f32x2 sv[8],
                                     const f32x2* csq, const f32x2* csk, const f32x2* csv,
                                     int lane) {
#define INITQ3(j) { \
        f32x2 aq = csq[2*(j)],   ak = csk[2*(j)],   av = csv[2*(j)];   \
        rot_rx<8-(j)>(sq, aq.x, aq.y, lane);                           \
        rot_rx<8-(j)>(sk, ak.x, ak.y, lane);                           \
        rot_rx<8-(j)>(sv, av.x, av.y, lane);                           \
        f32x2 bq = csq[2*(j)+1], bk = csk[2*(j)+1], bv = csv[2*(j)+1]; \
        rot_ry<8-(j)>(sq, bq.x, bq.y, lane);                           \
        rot_ry<8-(j)>(sk, bk.x, bk.y, lane);                           \
        rot_ry<8-(j)>(sv, bv.x, bv.y, lane); }
    INITQ3(0) INITQ3(1) INITQ3(2) INITQ3(3) INITQ3(4)
    INITQ3(5) INITQ3(6) INITQ3(7) INITQ3(8)
#undef INITQ3
    const f32x2 *pq = csq + 18, *pk = csk + 18, *pv = csv + 18;
#pragma unroll 1
    for (int L = 0; L < DVAR; ++L) {
        ring(sq, lane);
        ring(sk, lane);
        ring(sv, lane);
#define RY3(i, BJ) { f32x2 a = pq[i], b = pk[i], c = pv[i];            \
        rot_ry<BJ>(sq, a.x, a.y, lane);                                \
        rot_ry<BJ>(sk, b.x, b.y, lane);                                \
        rot_ry<BJ>(sv, c.x, c.y, lane); }
        RY3(0, 8) RY3(1, 7) RY3(2, 6) RY3(3, 5) RY3(4, 4)
        RY3(5, 3) RY3(6, 2) RY3(7, 1) RY3(8, 0)
#undef RY3
        pq += 9; pk += 9; pv += 9;
    }
}

// <Z>, <X>, <Y> on qubit with state-bit BJ.
template<int BJ>
__device__ __forceinline__ void expv(const f32x2 st[8], int lane, float& ez, float& ex, float& ey) {
    ez = ex = ey = 0.f;
    if constexpr (BJ >= 3) {
        constexpr int lm = 1 << (BJ - 3);
        const float sgn = (lane & lm) ? -1.f : 1.f;
#pragma unroll
        for (int r = 0; r < 8; ++r) {
            float px = lx<lm>(st[r].x, lane);
            float py = lx<lm>(st[r].y, lane);
            ez += sgn * (st[r].x * st[r].x + st[r].y * st[r].y);
            ex += st[r].x * px + st[r].y * py;
            ey += sgn * (st[r].x * py - st[r].y * px);
        }
    } else {
        constexpr int M = 1 << BJ;
#pragma unroll
        for (int r = 0; r < 8; ++r) {
            if ((r & M) == 0) {
                f32x2 a = st[r], b = st[r + M];
                ez += (a.x * a.x + a.y * a.y) - (b.x * b.x + b.y * b.y);
                ex += 2.f * (a.x * b.x + a.y * b.y);
                ey += 2.f * (a.x * b.y - a.y * b.x);
            }
        }
    }
    ez = wave_sum(ez, lane); ex = wave_sum(ex, lane); ey = wave_sum(ey, lane);
}

__global__ __launch_bounds__(256) void sim_kernel(
    const float* __restrict__ inp, const float* __restrict__ wq,
    const float* __restrict__ wk,  const float* __restrict__ wv,
    float* __restrict__ outQ, float* __restrict__ outK, float* __restrict__ outV)
{
    __shared__ f32x2 cs_all[4][54 + 270];   // per-wave {cos(t/2), sin(t/2)} tables

    const int warp = threadIdx.x >> 6;
    const int lane = threadIdx.x & 63;
    const int fi   = blockIdx.x * 4 + warp; // flat = s*B + b
    const int b = fi % B_DIM, s = fi / B_DIM;
    const float* x = inp + ((size_t)b * S_DIM + s) * D_DIM;
    f32x2* cs = cs_all[warp];

    for (int k = lane; k < 324; k += 64) {
        float ang = (k < 54)  ? x[k]
                  : (k < 144) ? wq[k - 54]
                  : (k < 234) ? wk[k - 144]
                              : wv[k - 234];
        float sn, cn; sincosf(0.5f * ang, &sn, &cn);
        f32x2 v = {cn, sn};
        cs[k] = v;
    }
    // wave-local LDS use only: no __syncthreads needed

    f32x2 sq[8], sk[8], sv[8];
#pragma unroll
    for (int r = 0; r < 8; ++r) { f32x2 z = {0.f, 0.f}; sq[r] = z; }
    if (lane == 0) sq[0].x = 1.f;

    // Shared encoding circuit on sq, then fork.
    run_circuit(sq, cs, DENC, lane);
#pragma unroll
    for (int r = 0; r < 8; ++r) { sk[r] = sq[r]; sv[r] = sq[r]; }

    // Three variational circuits interleaved (3x ILP).
    run3(sq, sk, sv, cs + 54, cs + 144, cs + 234, lane);

    // ---- Q: <Z_0> (qubit 0 = state bit 8 = lane bit 5) ----
    {
        float p = 0.f;
#pragma unroll
        for (int r = 0; r < 8; ++r) p += sq[r].x * sq[r].x + sq[r].y * sq[r].y;
        p = (lane & 32) ? -p : p;
        p = wave_sum(p, lane);
        if (lane == 0) outQ[fi] = p;
    }
    // ---- K ----
    {
        float p = 0.f;
#pragma unroll
        for (int r = 0; r < 8; ++r) p += sk[r].x * sk[r].x + sk[r].y * sk[r].y;
        p = (lane & 32) ? -p : p;
        p = wave_sum(p, lane);
        if (lane == 0) outK[fi] = p;
    }
    // ---- V ----
    {
        float* vrow = outV + (size_t)fi * D_DIM;
#define EXPQ(q) { float ez, ex, ey; expv<8 - (q)>(sv, lane, ez, ex, ey);            \
                  if (lane == 0) { vrow[(q)] = ez; vrow[9 + (q)] = ex;              \
                                   vrow[18 + (q)] = ey; vrow[27 + (q)] = ez;        \
                                   vrow[36 + (q)] = ex; vrow[45 + (q)] = ey; } }
        EXPQ(0) EXPQ(1) EXPQ(2) EXPQ(3) EXPQ(4)
        EXPQ(5) EXPQ(6) EXPQ(7) EXPQ(8)
#undef EXPQ
    }
}

__global__ __launch_bounds__(256) void attn_kernel(
    const float* __restrict__ inp, const float* __restrict__ Q,
    const float* __restrict__ K,   const float* __restrict__ V,
    float* __restrict__ out)
{
    __shared__ float w4[4][S_DIM];
    const int warp = threadIdx.x >> 6;
    const int t    = threadIdx.x & 63;
    const int bi   = blockIdx.x * 4 + warp;   // b*S + i
    const int b    = bi / S_DIM;
    const int i    = bi % S_DIM;
    float* w = w4[warp];

    const float q = Q[i * B_DIM + b];
    float e0, e1 = 0.f;
    {
        float d0 = q - K[t * B_DIM + b];
        e0 = expf(-d0 * d0);
        w[t] = e0;
        if (t < S_DIM - 64) {
            float d1 = q - K[(t + 64) * B_DIM + b];
            e1 = expf(-d1 * d1);
            w[t + 64] = e1;
        }
    }
    float ps = wave_sum(e0 + e1, t);
    const float inv = 1.f / ps;

    if (t < D_DIM) {
        float acc = 0.f;
        for (int j = 0; j < S_DIM; ++j)
            acc += w[j] * V[(size_t)(j * B_DIM + b) * D_DIM + t];
        size_t o = (size_t)bi * D_DIM + t;
        out[o] = inp[o] + acc * inv;
    }
}

extern "C" void kernel_launch(void* const* d_in, const int* in_sizes, int n_in,
                              void* d_out, int out_size, void* d_ws, size_t ws_size,
                              hipStream_t stream)
{
    (void)in_sizes; (void)n_in; (void)out_size; (void)ws_size;
    const float* inp = (const float*)d_in[0];
    const float* wq  = (const float*)d_in[1];
    const float* wk  = (const float*)d_in[2];
    const float* wv  = (const float*)d_in[3];
    float* outp = (float*)d_out;

    float* Qw = (float*)d_ws;
    float* Kw = Qw + NFLAT;
    float* Vw = Kw + NFLAT;

    sim_kernel<<<NFLAT / 4, 256, 0, stream>>>(inp, wq, wk, wv, Qw, Kw, Vw);
    attn_kernel<<<NFLAT / 4, 256, 0, stream>>>(inp, Qw, Kw, Vw, outp);
}

// Round 8
// 127.670 us; speedup vs baseline: 3.6965x; 1.2071x over previous
//
#include <hip/hip_runtime.h>
#include <math.h>

#define NQ     9
#define B_DIM  48
#define S_DIM  96
#define D_DIM  54
#define DENC   4
#define DVAR   8
#define NFLAT  (B_DIM * S_DIM)   // 4608

typedef float f32x2 __attribute__((ext_vector_type(2)));

// Masked DPP: lanes enabled by row_mask/bank_mask get DPP-selected src; others keep old.
template<int CTRL, int RM, int BM>
__device__ __forceinline__ float mdpp(float old_, float src) {
    return __int_as_float(__builtin_amdgcn_update_dpp(
        __float_as_int(old_), __float_as_int(src), CTRL, RM, BM, false));
}

// Lane-xor primitives — R5/R7 hardware-validated set.
template<int LM>
__device__ __forceinline__ float lx(float v, int lane) {
    int x = __float_as_int(v);
    if constexpr (LM == 1)       x = __builtin_amdgcn_update_dpp(x, x, 0xB1, 0xF, 0xF, true);  // quad[1,0,3,2]
    else if constexpr (LM == 2)  x = __builtin_amdgcn_update_dpp(x, x, 0x4E, 0xF, 0xF, true);  // quad[2,3,0,1]
    else if constexpr (LM == 4)  x = __builtin_amdgcn_ds_swizzle(x, 0x101F);                   // xor4
    else if constexpr (LM == 8)  x = __builtin_amdgcn_update_dpp(x, x, 0x128, 0xF, 0xF, true); // ROW_ROR:8
    else if constexpr (LM == 16) x = __builtin_amdgcn_ds_swizzle(x, 0x401F);                   // xor16
    else {
        auto r = __builtin_amdgcn_permlane32_swap(x, x, false, false);
        // ret[0] = [lo,lo], ret[1] = [hi,hi]; want [hi,lo]
        x = (lane & 32) ? r[0] : r[1];
    }
    return __int_as_float(x);
}

__device__ __forceinline__ float wave_sum(float v, int lane) {
    v += lx<32>(v, lane);
    v += lx<16>(v, lane);
    v += lx<8>(v, lane);
    v += lx<4>(v, lane);
    v += lx<2>(v, lane);
    v += lx<1>(v, lane);
    return v;
}

// State layout: amp index i (9 bits) -> lane = i>>3 (bits 8..3), reg r = i&7 (bits 2..0).
// Qubit j <-> state bit BJ = 8-j.

// CNOT ring (control j, target (j+1)%9): state-bit pairs (8,7)(7,6)...(1,0)(0,8).
// Stages (8,7)(7,6)(6,5)(5,4)(4,3) touch ONLY lane bits; their composite index map is
// b_t ^= b_{t+1} for t=3..7, i.e. dst lane L pulls from src lane L^(L>>1) (Gray code).
// One ds_bpermute per component replaces the whole masked-DPP cascade.
// Spot-checked vs the R5 stage-by-stage code: A5[1]=A0[1], A5[2]=A0[3], A5[48]=A0[40].
__device__ __forceinline__ void ring(f32x2 st[8], int lane) {
    const int gray = (lane ^ (lane >> 1)) << 2;   // loop-invariant, LICM-hoisted
#pragma unroll
    for (int r = 0; r < 8; ++r) {
        st[r].x = __int_as_float(__builtin_amdgcn_ds_bpermute(gray, __float_as_int(st[r].x)));
        st[r].y = __int_as_float(__builtin_amdgcn_ds_bpermute(gray, __float_as_int(st[r].y)));
    }
    // (3,2): ctrl lane bit0 (b3), tgt reg bit2
    {
        const bool c0 = (lane & 1) != 0;
#pragma unroll
        for (int r = 0; r < 4; ++r) {
            f32x2 a = st[r], b = st[r + 4];
            st[r]     = c0 ? b : a;
            st[r + 4] = c0 ? a : b;
        }
    }
    // (2,1): regs with bit2: r <-> r^2 (rename)
    { f32x2 t = st[4]; st[4] = st[6]; st[6] = t; }
    { f32x2 t = st[5]; st[5] = st[7]; st[7] = t; }
    // (1,0): regs with bit1: r <-> r^1 (rename)
    { f32x2 t = st[2]; st[2] = st[3]; st[3] = t; }
    { f32x2 t = st[6]; st[6] = st[7]; st[7] = t; }
    // (0,8): odd regs: xor32
#pragma unroll
    for (int r = 1; r < 8; r += 2) {
        st[r].x = lx<32>(st[r].x, lane);
        st[r].y = lx<32>(st[r].y, lane);
    }
}

template<int BJ>
__device__ __forceinline__ void rot_ry(f32x2 st[8], float c, float s, int lane) {
    const f32x2 c2 = {c, c};
    if constexpr (BJ >= 3) {
        constexpr int lm = 1 << (BJ - 3);
        const float sg = (lane & lm) ? s : -s;
        const f32x2 sg2 = {sg, sg};
#pragma unroll
        for (int r = 0; r < 8; ++r) {
            f32x2 p = { lx<lm>(st[r].x, lane), lx<lm>(st[r].y, lane) };
            st[r] = st[r] * c2 + p * sg2;
        }
    } else {
        constexpr int M = 1 << BJ;
        const f32x2 s2 = {s, s}, ns2 = {-s, -s};
#pragma unroll
        for (int r = 0; r < 8; ++r) {
            if ((r & M) == 0) {
                f32x2 a = st[r], b = st[r + M];
                st[r]     = a * c2 + b * ns2;
                st[r + M] = b * c2 + a * s2;
            }
        }
    }
}

template<int BJ>
__device__ __forceinline__ void rot_rx(f32x2 st[8], float c, float s, int lane) {
    if constexpr (BJ >= 3) {
        constexpr int lm = 1 << (BJ - 3);
#pragma unroll
        for (int r = 0; r < 8; ++r) {
            float px = lx<lm>(st[r].x, lane), py = lx<lm>(st[r].y, lane);
            float nx = fmaf(s, py, c * st[r].x);
            float ny = fmaf(-s, px, c * st[r].y);
            st[r].x = nx; st[r].y = ny;
        }
    } else {
        constexpr int M = 1 << BJ;
#pragma unroll
        for (int r = 0; r < 8; ++r) {
            if ((r & M) == 0) {
                f32x2 a = st[r], b = st[r + M];
                st[r].x     = fmaf(s, b.y, c * a.x);
                st[r].y     = fmaf(-s, b.x, c * a.y);
                st[r + M].x = fmaf(s, a.y, c * b.x);
                st[r + M].y = fmaf(-s, a.x, c * b.y);
            }
        }
    }
}

#define INITQ(j) { f32x2 c0 = cs[2 * (j)], c1 = cs[2 * (j) + 1];      \
                   rot_rx<8 - (j)>(st, c0.x, c0.y, lane);             \
                   rot_ry<8 - (j)>(st, c1.x, c1.y, lane); }

// Single-stream circuit (encoding phase).
__device__ __forceinline__ void run_circuit(f32x2 st[8], const f32x2* cs, int layers, int lane) {
    INITQ(0) INITQ(1) INITQ(2) INITQ(3) INITQ(4)
    INITQ(5) INITQ(6) INITQ(7) INITQ(8)
    const f32x2* p = cs + 18;
#pragma unroll 1
    for (int L = 0; L < layers; ++L) {
        ring(st, lane);
        { f32x2 cc = p[0]; rot_ry<8>(st, cc.x, cc.y, lane); }
        { f32x2 cc = p[1]; rot_ry<7>(st, cc.x, cc.y, lane); }
        { f32x2 cc = p[2]; rot_ry<6>(st, cc.x, cc.y, lane); }
        { f32x2 cc = p[3]; rot_ry<5>(st, cc.x, cc.y, lane); }
        { f32x2 cc = p[4]; rot_ry<4>(st, cc.x, cc.y, lane); }
        { f32x2 cc = p[5]; rot_ry<3>(st, cc.x, cc.y, lane); }
        { f32x2 cc = p[6]; rot_ry<2>(st, cc.x, cc.y, lane); }
        { f32x2 cc = p[7]; rot_ry<1>(st, cc.x, cc.y, lane); }
        { f32x2 cc = p[8]; rot_ry<0>(st, cc.x, cc.y, lane); }
        p += 9;
    }
}

// Three independent variational circuits (Q,K,V) interleaved for ILP.
__device__ __forceinline__ void run3(f32x2 sq[8], f32x2 sk[8], f32x2 sv[8],
                                     const f32x2* csq, const f32x2* csk, const f32x2* csv,
                                     int lane) {
#define INITQ3(j) { \
        f32x2 aq = csq[2*(j)],   ak = csk[2*(j)],   av = csv[2*(j)];   \
        rot_rx<8-(j)>(sq, aq.x, aq.y, lane);                           \
        rot_rx<8-(j)>(sk, ak.x, ak.y, lane);                           \
        rot_rx<8-(j)>(sv, av.x, av.y, lane);                           \
        f32x2 bq = csq[2*(j)+1], bk = csk[2*(j)+1], bv = csv[2*(j)+1]; \
        rot_ry<8-(j)>(sq, bq.x, bq.y, lane);                           \
        rot_ry<8-(j)>(sk, bk.x, bk.y, lane);                           \
        rot_ry<8-(j)>(sv, bv.x, bv.y, lane); }
    INITQ3(0) INITQ3(1) INITQ3(2) INITQ3(3) INITQ3(4)
    INITQ3(5) INITQ3(6) INITQ3(7) INITQ3(8)
#undef INITQ3
    const f32x2 *pq = csq + 18, *pk = csk + 18, *pv = csv + 18;
#pragma unroll 1
    for (int L = 0; L < DVAR; ++L) {
        ring(sq, lane);
        ring(sk, lane);
        ring(sv, lane);
#define RY3(i, BJ) { f32x2 a = pq[i], b = pk[i], c = pv[i];            \
        rot_ry<BJ>(sq, a.x, a.y, lane);                                \
        rot_ry<BJ>(sk, b.x, b.y, lane);                                \
        rot_ry<BJ>(sv, c.x, c.y, lane); }
        RY3(0, 8) RY3(1, 7) RY3(2, 6) RY3(3, 5) RY3(4, 4)
        RY3(5, 3) RY3(6, 2) RY3(7, 1) RY3(8, 0)
#undef RY3
        pq += 9; pk += 9; pv += 9;
    }
}

// <Z>, <X>, <Y> on qubit with state-bit BJ.
template<int BJ>
__device__ __forceinline__ void expv(const f32x2 st[8], int lane, float& ez, float& ex, float& ey) {
    ez = ex = ey = 0.f;
    if constexpr (BJ >= 3) {
        constexpr int lm = 1 << (BJ - 3);
        const float sgn = (lane & lm) ? -1.f : 1.f;
#pragma unroll
        for (int r = 0; r < 8; ++r) {
            float px = lx<lm>(st[r].x, lane);
            float py = lx<lm>(st[r].y, lane);
            ez += sgn * (st[r].x * st[r].x + st[r].y * st[r].y);
            ex += st[r].x * px + st[r].y * py;
            ey += sgn * (st[r].x * py - st[r].y * px);
        }
    } else {
        constexpr int M = 1 << BJ;
#pragma unroll
        for (int r = 0; r < 8; ++r) {
            if ((r & M) == 0) {
                f32x2 a = st[r], b = st[r + M];
                ez += (a.x * a.x + a.y * a.y) - (b.x * b.x + b.y * b.y);
                ex += 2.f * (a.x * b.x + a.y * b.y);
                ey += 2.f * (a.x * b.y - a.y * b.x);
            }
        }
    }
    ez = wave_sum(ez, lane); ex = wave_sum(ex, lane); ey = wave_sum(ey, lane);
}

__global__ __launch_bounds__(64, 5) void sim_kernel(
    const float* __restrict__ inp, const float* __restrict__ wq,
    const float* __restrict__ wk,  const float* __restrict__ wv,
    float* __restrict__ outQ, float* __restrict__ outK, float* __restrict__ outV)
{
    __shared__ f32x2 cs[54 + 270];   // {cos(t/2), sin(t/2)} per angle

    const int lane = threadIdx.x;
    const int fi   = blockIdx.x;     // flat = s*B + b; 4608 blocks = 18 waves/CU exactly
    const int b = fi % B_DIM, s = fi / B_DIM;
    const float* x = inp + ((size_t)b * S_DIM + s) * D_DIM;

    for (int k = lane; k < 324; k += 64) {
        float ang = (k < 54)  ? x[k]
                  : (k < 144) ? wq[k - 54]
                  : (k < 234) ? wk[k - 144]
                              : wv[k - 234];
        float sn, cn; sincosf(0.5f * ang, &sn, &cn);
        f32x2 v = {cn, sn};
        cs[k] = v;
    }
    // single wave: LDS write->read ordering handled by lgkmcnt, no barrier needed

    f32x2 sq[8], sk[8], sv[8];
#pragma unroll
    for (int r = 0; r < 8; ++r) { f32x2 z = {0.f, 0.f}; sq[r] = z; }
    if (lane == 0) sq[0].x = 1.f;

    // Shared encoding circuit on sq, then fork.
    run_circuit(sq, cs, DENC, lane);
#pragma unroll
    for (int r = 0; r < 8; ++r) { sk[r] = sq[r]; sv[r] = sq[r]; }

    run3(sq, sk, sv, cs + 54, cs + 144, cs + 234, lane);

    // ---- Q: <Z_0> (qubit 0 = state bit 8 = lane bit 5) ----
    {
        float p = 0.f;
#pragma unroll
        for (int r = 0; r < 8; ++r) p += sq[r].x * sq[r].x + sq[r].y * sq[r].y;
        p = (lane & 32) ? -p : p;
        p = wave_sum(p, lane);
        if (lane == 0) outQ[fi] = p;
    }
    // ---- K ----
    {
        float p = 0.f;
#pragma unroll
        for (int r = 0; r < 8; ++r) p += sk[r].x * sk[r].x + sk[r].y * sk[r].y;
        p = (lane & 32) ? -p : p;
        p = wave_sum(p, lane);
        if (lane == 0) outK[fi] = p;
    }
    // ---- V ----
    {
        float* vrow = outV + (size_t)fi * D_DIM;
#define EXPQ(q) { float ez, ex, ey; expv<8 - (q)>(sv, lane, ez, ex, ey);            \
                  if (lane == 0) { vrow[(q)] = ez; vrow[9 + (q)] = ex;              \
                                   vrow[18 + (q)] = ey; vrow[27 + (q)] = ez;        \
                                   vrow[36 + (q)] = ex; vrow[45 + (q)] = ey; } }
        EXPQ(0) EXPQ(1) EXPQ(2) EXPQ(3) EXPQ(4)
        EXPQ(5) EXPQ(6) EXPQ(7) EXPQ(8)
#undef EXPQ
    }
}

__global__ __launch_bounds__(256) void attn_kernel(
    const float* __restrict__ inp, const float* __restrict__ Q,
    const float* __restrict__ K,   const float* __restrict__ V,
    float* __restrict__ out)
{
    __shared__ float w4[4][S_DIM];
    const int warp = threadIdx.x >> 6;
    const int t    = threadIdx.x & 63;
    const int bi   = blockIdx.x * 4 + warp;   // b*S + i
    const int b    = bi / S_DIM;
    const int i    = bi % S_DIM;
    float* w = w4[warp];

    const float q = Q[i * B_DIM + b];
    float e0, e1 = 0.f;
    {
        float d0 = q - K[t * B_DIM + b];
        e0 = expf(-d0 * d0);
        w[t] = e0;
        if (t < S_DIM - 64) {
            float d1 = q - K[(t + 64) * B_DIM + b];
            e1 = expf(-d1 * d1);
            w[t + 64] = e1;
        }
    }
    float ps = wave_sum(e0 + e1, t);
    const float inv = 1.f / ps;

    if (t < D_DIM) {
        float acc = 0.f;
        for (int j = 0; j < S_DIM; ++j)
            acc += w[j] * V[(size_t)(j * B_DIM + b) * D_DIM + t];
        size_t o = (size_t)bi * D_DIM + t;
        out[o] = inp[o] + acc * inv;
    }
}

extern "C" void kernel_launch(void* const* d_in, const int* in_sizes, int n_in,
                              void* d_out, int out_size, void* d_ws, size_t ws_size,
                              hipStream_t stream)
{
    (void)in_sizes; (void)n_in; (void)out_size; (void)ws_size;
    const float* inp = (const float*)d_in[0];
    const float* wq  = (const float*)d_in[1];
    const float* wk  = (const float*)d_in[2];
    const float* wv  = (const float*)d_in[3];
    float* outp = (float*)d_out;

    float* Qw = (float*)d_ws;
    float* Kw = Qw + NFLAT;
    float* Vw = Kw + NFLAT;

    sim_kernel<<<NFLAT, 64, 0, stream>>>(inp, wq, wk, wv, Qw, Kw, Vw);
    attn_kernel<<<NFLAT / 4, 256, 0, stream>>>(inp, Qw, Kw, Vw, outp);
}